// Round 1
// baseline (6643.273 us; speedup 1.0000x reference)
//
#include <hip/hip_runtime.h>
#include <cmath>

// Problem constants (S=16384, DIM=1280, H=16, D=80, G=16, L=1024)
#define SEQ   16384
#define DIMV  1280
#define NH    16
#define HD    80
#define NG    16
#define GL    1024

// ---------------------------------------------------------------------------
// Tiled fp32 GEMM: C[M x N] = A[M x K] @ B[K x N] + bias
// 128x128 tile per block, 256 threads, 8x8 accum per thread, K-tile = 16.
// M, N, K must be multiples of 128/128/16 (true for both uses here).
// ---------------------------------------------------------------------------
__global__ __launch_bounds__(256) void gemm_tile_kernel(
    const float* __restrict__ A, int lda,
    const float* __restrict__ B, int ldb,
    const float* __restrict__ bias,
    float* __restrict__ C, int ldc,
    int K)
{
    __shared__ float As[16][132];   // transposed A tile: As[k][m]
    __shared__ float Bs[16][132];   // Bs[k][n]
    const int t  = threadIdx.x;
    const int tx = t & 15, ty = t >> 4;
    const int bm = blockIdx.y * 128, bn = blockIdx.x * 128;

    float acc[8][8];
#pragma unroll
    for (int i = 0; i < 8; ++i)
#pragma unroll
        for (int j = 0; j < 8; ++j) acc[i][j] = 0.f;

    for (int kt = 0; kt < K; kt += 16) {
        // Load A tile (128 rows x 16 cols) as float4, store transposed.
#pragma unroll
        for (int i = 0; i < 2; ++i) {
            int f = t + i * 256;
            int r = f >> 2, c = f & 3;
            float4 v = *(const float4*)&A[(size_t)(bm + r) * lda + kt + c * 4];
            As[c * 4 + 0][r] = v.x;
            As[c * 4 + 1][r] = v.y;
            As[c * 4 + 2][r] = v.z;
            As[c * 4 + 3][r] = v.w;
        }
        // Load B tile (16 rows x 128 cols) as float4.
#pragma unroll
        for (int i = 0; i < 2; ++i) {
            int f = t + i * 256;
            int r = f >> 5, c = f & 31;
            *(float4*)&Bs[r][c * 4] =
                *(const float4*)&B[(size_t)(kt + r) * ldb + bn + c * 4];
        }
        __syncthreads();

#pragma unroll
        for (int kk = 0; kk < 16; ++kk) {
            float a[8], b[8];
            *(float4*)&a[0] = *(float4*)&As[kk][ty * 8];
            *(float4*)&a[4] = *(float4*)&As[kk][ty * 8 + 4];
            *(float4*)&b[0] = *(float4*)&Bs[kk][tx * 8];
            *(float4*)&b[4] = *(float4*)&Bs[kk][tx * 8 + 4];
#pragma unroll
            for (int i = 0; i < 8; ++i)
#pragma unroll
                for (int j = 0; j < 8; ++j)
                    acc[i][j] = fmaf(a[i], b[j], acc[i][j]);
        }
        __syncthreads();
    }

    // Epilogue: add bias, store.
#pragma unroll
    for (int i = 0; i < 8; ++i) {
        size_t row = (size_t)(bm + ty * 8 + i);
#pragma unroll
        for (int j = 0; j < 8; j += 4) {
            int col = bn + tx * 8 + j;
            float4 bv = *(const float4*)&bias[col];
            float4 v;
            v.x = acc[i][j + 0] + bv.x;
            v.y = acc[i][j + 1] + bv.y;
            v.z = acc[i][j + 2] + bv.z;
            v.w = acc[i][j + 3] + bv.w;
            *(float4*)&C[row * (size_t)ldc + col] = v;
        }
    }
}

// ---------------------------------------------------------------------------
// RoPE in-place on q and k sections of qkv (S x 3840; q=[0,1280), k=[1280,2560)).
// Pair rotation: (x_d, x_{d+40}) -> (x_d*c - x_{d+40}*s, x_{d+40}*c + x_d*s)
// with c = cos[s][d], s = sin[s][d] (cos[d] == cos[d+40] by construction).
// ---------------------------------------------------------------------------
__global__ __launch_bounds__(256) void rope_kernel(
    float* __restrict__ qkv,
    const float* __restrict__ cos_t,
    const float* __restrict__ sin_t)
{
    int u = blockIdx.x * 256 + threadIdx.x;
    if (u >= SEQ * NH * 40) return;
    int s   = u / (NH * 40);
    int rem = u % (NH * 40);
    int h   = rem / 40;
    int d   = rem % 40;

    float c  = cos_t[s * HD + d];
    float sn = sin_t[s * HD + d];
    size_t base = (size_t)s * (3 * DIMV) + h * HD + d;

    float q0 = qkv[base],        q1 = qkv[base + 40];
    qkv[base]        = q0 * c - q1 * sn;
    qkv[base + 40]   = q1 * c + q0 * sn;

    float k0 = qkv[base + DIMV], k1 = qkv[base + DIMV + 40];
    qkv[base + DIMV]      = k0 * c - k1 * sn;
    qkv[base + DIMV + 40] = k1 * c + k0 * sn;
}

// ---------------------------------------------------------------------------
// Flash-style attention. One block = (group g, head h, 32-query tile).
// K/V staged in LDS in chunks of 64 rows; online softmax; O in registers.
// Output written back into the q slot of qkv (safe: each q row/col-slice is
// read only by the block that owns it, at block start).
// scale = 1/D = 1/80 (per reference; NOT 1/sqrt(D)).
// ---------------------------------------------------------------------------
__global__ __launch_bounds__(256) void attn_kernel(float* __restrict__ qkv)
{
    const int bx = blockIdx.x;
    const int qt = bx & 31;          // 32 query tiles of 32
    const int h  = (bx >> 5) & 15;
    const int g  = bx >> 9;

    __shared__ float Qs[32][84];     // rows padded to 84 (16B aligned, conflict-free)
    __shared__ float Ks[64][84];
    __shared__ float Vs[64][84];
    __shared__ float St[64][36];     // P transposed: St[k][q], pad 36

    const int t     = threadIdx.x;
    const int q     = t >> 3;        // 0..31, same in both phases
    const int lane8 = t & 7;

    // Load Q tile: 32 rows x 80 floats = 640 float4.
    for (int i = t; i < 32 * 20; i += 256) {
        int r = i / 20, c = i % 20;
        *(float4*)&Qs[r][c * 4] = *(const float4*)
            &qkv[(size_t)(g * GL + qt * 32 + r) * (3 * DIMV) + h * HD + c * 4];
    }

    float O[10];
#pragma unroll
    for (int i = 0; i < 10; ++i) O[i] = 0.f;
    float m_loc = -1e30f, l_loc = 0.f;

    const float scale = 1.0f / 80.0f;
    __syncthreads();

    for (int kc = 0; kc < GL / 64; ++kc) {
        // Load K and V chunks: 64 rows x 80 floats each.
        for (int i = t; i < 64 * 20; i += 256) {
            int r = i / 20, c = i % 20;
            size_t rowbase =
                (size_t)(g * GL + kc * 64 + r) * (3 * DIMV) + h * HD + c * 4;
            *(float4*)&Ks[r][c * 4] = *(const float4*)&qkv[rowbase + DIMV];
            *(float4*)&Vs[r][c * 4] = *(const float4*)&qkv[rowbase + 2 * DIMV];
        }
        __syncthreads();

        // Scores: thread computes 8 scores for query q, keys k0..k0+7.
        const int k0 = lane8 * 8;
        float sc[8];
#pragma unroll
        for (int j = 0; j < 8; ++j) sc[j] = 0.f;
        for (int d4 = 0; d4 < 20; ++d4) {
            float4 qf = *(float4*)&Qs[q][d4 * 4];
#pragma unroll
            for (int j = 0; j < 8; ++j) {
                float4 kf = *(float4*)&Ks[k0 + j][d4 * 4];
                sc[j] = fmaf(qf.x, kf.x,
                        fmaf(qf.y, kf.y,
                        fmaf(qf.z, kf.z,
                        fmaf(qf.w, kf.w, sc[j]))));
            }
        }

        float rmax = -1e30f;
#pragma unroll
        for (int j = 0; j < 8; ++j) {
            sc[j] *= scale;
            rmax = fmaxf(rmax, sc[j]);
        }
#pragma unroll
        for (int off = 1; off < 8; off <<= 1)
            rmax = fmaxf(rmax, __shfl_xor(rmax, off, 64));

        float mnew  = fmaxf(m_loc, rmax);
        float alpha = __expf(m_loc - mnew);
        float rsum  = 0.f;
#pragma unroll
        for (int j = 0; j < 8; ++j) {
            sc[j] = __expf(sc[j] - mnew);
            rsum += sc[j];
            St[k0 + j][q] = sc[j];
        }
#pragma unroll
        for (int off = 1; off < 8; off <<= 1)
            rsum += __shfl_xor(rsum, off, 64);
        l_loc = l_loc * alpha + rsum;
        m_loc = mnew;
        __syncthreads();   // St complete

        // PV: thread owns query q, dims d = 2*lane8 + 16*i (+0,+1), i<5.
#pragma unroll
        for (int i = 0; i < 10; ++i) O[i] *= alpha;
        for (int k = 0; k < 64; ++k) {
            float p = St[k][q];
#pragma unroll
            for (int i = 0; i < 5; ++i) {
                float2 vv = *(float2*)&Vs[k][2 * lane8 + 16 * i];
                O[2 * i + 0] = fmaf(p, vv.x, O[2 * i + 0]);
                O[2 * i + 1] = fmaf(p, vv.y, O[2 * i + 1]);
            }
        }
        __syncthreads();   // before next chunk overwrites Ks/Vs
    }

    // Epilogue: normalize, write into q slot of qkv.
    float inv_l = 1.0f / l_loc;
    size_t obase = (size_t)(g * GL + qt * 32 + q) * (3 * DIMV) + h * HD;
#pragma unroll
    for (int i = 0; i < 5; ++i) {
        float2 vv;
        vv.x = O[2 * i + 0] * inv_l;
        vv.y = O[2 * i + 1] * inv_l;
        *(float2*)&qkv[obase + 2 * lane8 + 16 * i] = vv;
    }
}

// ---------------------------------------------------------------------------
// Launch
// ---------------------------------------------------------------------------
extern "C" void kernel_launch(void* const* d_in, const int* in_sizes, int n_in,
                              void* d_out, int out_size, void* d_ws, size_t ws_size,
                              hipStream_t stream)
{
    const float* hidden = (const float*)d_in[0];   // (16384, 1280)
    const float* cos_t  = (const float*)d_in[1];   // (16384, 80)
    const float* sin_t  = (const float*)d_in[2];   // (16384, 80)
    const float* w_qkv  = (const float*)d_in[3];   // (1280, 3840)
    const float* b_qkv  = (const float*)d_in[4];   // (3840,)
    const float* w_proj = (const float*)d_in[5];   // (1280, 1280)
    const float* b_proj = (const float*)d_in[6];   // (1280,)
    // d_in[7] = cu_seqlens: uniform groups of 1024; unused.

    float* out = (float*)d_out;                    // (16384, 1280)
    float* qkv = (float*)d_ws;                     // (16384, 3840) scratch

    // 1) QKV projection: qkv = hidden @ w_qkv + b_qkv
    {
        dim3 grid(3 * DIMV / 128, SEQ / 128);      // (30, 128)
        gemm_tile_kernel<<<grid, 256, 0, stream>>>(
            hidden, DIMV, w_qkv, 3 * DIMV, b_qkv, qkv, 3 * DIMV, DIMV);
    }

    // 2) RoPE on q and k, in place.
    {
        int n = SEQ * NH * 40;
        rope_kernel<<<(n + 255) / 256, 256, 0, stream>>>(qkv, cos_t, sin_t);
    }

    // 3) Attention (writes O into the q slot of qkv).
    {
        dim3 grid(NG * NH * (GL / 32));            // 8192 blocks
        attn_kernel<<<grid, 256, 0, stream>>>(qkv);
    }

    // 4) Output projection: out = attn_out @ w_proj + b_proj
    //    attn_out lives in the q slot of qkv -> lda = 3840.
    {
        dim3 grid(DIMV / 128, SEQ / 128);          // (10, 128)
        gemm_tile_kernel<<<grid, 256, 0, stream>>>(
            qkv, 3 * DIMV, w_proj, DIMV, b_proj, out, DIMV, DIMV);
    }
}

// Round 3
// 2959.060 us; speedup vs baseline: 2.2451x; 2.2451x over previous
//
#include <hip/hip_runtime.h>
#include <cmath>

// Problem constants (S=16384, DIM=1280, H=16, D=80, G=16, L=1024)
#define SEQ   16384
#define DIMV  1280
#define NH    16
#define HD    80
#define NG    16
#define GL    1024
#define LDQKV (3*DIMV)

typedef short s16x8 __attribute__((ext_vector_type(8)));
typedef float f32x4 __attribute__((ext_vector_type(4)));

__device__ __forceinline__ unsigned short f2bf(float f) {
    union { float f; unsigned int u; } v; v.f = f;
    unsigned int u = v.u;
    return (unsigned short)((u + 0x7FFFu + ((u >> 16) & 1u)) >> 16);  // RNE
}
__device__ __forceinline__ unsigned int pack2(float a, float b) {
    return (unsigned int)f2bf(a) | ((unsigned int)f2bf(b) << 16);
}

// ---------------------------------------------------------------------------
// Tiled fp32 GEMM: C[M x N] = A[M x K] @ B[K x N] + bias
// 128x128 tile per block, 256 threads, 8x8 accum per thread, K-tile = 16.
// ---------------------------------------------------------------------------
__global__ __launch_bounds__(256) void gemm_tile_kernel(
    const float* __restrict__ A, int lda,
    const float* __restrict__ B, int ldb,
    const float* __restrict__ bias,
    float* __restrict__ C, int ldc,
    int K)
{
    __shared__ float As[16][132];
    __shared__ float Bs[16][132];
    const int t  = threadIdx.x;
    const int tx = t & 15, ty = t >> 4;
    const int bm = blockIdx.y * 128, bn = blockIdx.x * 128;

    float acc[8][8];
#pragma unroll
    for (int i = 0; i < 8; ++i)
#pragma unroll
        for (int j = 0; j < 8; ++j) acc[i][j] = 0.f;

    for (int kt = 0; kt < K; kt += 16) {
#pragma unroll
        for (int i = 0; i < 2; ++i) {
            int f = t + i * 256;
            int r = f >> 2, c = f & 3;
            float4 v = *(const float4*)&A[(size_t)(bm + r) * lda + kt + c * 4];
            As[c * 4 + 0][r] = v.x;
            As[c * 4 + 1][r] = v.y;
            As[c * 4 + 2][r] = v.z;
            As[c * 4 + 3][r] = v.w;
        }
#pragma unroll
        for (int i = 0; i < 2; ++i) {
            int f = t + i * 256;
            int r = f >> 5, c = f & 31;
            *(float4*)&Bs[r][c * 4] =
                *(const float4*)&B[(size_t)(kt + r) * ldb + bn + c * 4];
        }
        __syncthreads();

#pragma unroll
        for (int kk = 0; kk < 16; ++kk) {
            float a[8], b[8];
            *(float4*)&a[0] = *(float4*)&As[kk][ty * 8];
            *(float4*)&a[4] = *(float4*)&As[kk][ty * 8 + 4];
            *(float4*)&b[0] = *(float4*)&Bs[kk][tx * 8];
            *(float4*)&b[4] = *(float4*)&Bs[kk][tx * 8 + 4];
#pragma unroll
            for (int i = 0; i < 8; ++i)
#pragma unroll
                for (int j = 0; j < 8; ++j)
                    acc[i][j] = fmaf(a[i], b[j], acc[i][j]);
        }
        __syncthreads();
    }

#pragma unroll
    for (int i = 0; i < 8; ++i) {
        size_t row = (size_t)(bm + ty * 8 + i);
#pragma unroll
        for (int j = 0; j < 8; j += 4) {
            int col = bn + tx * 8 + j;
            float4 bv = *(const float4*)&bias[col];
            float4 v;
            v.x = acc[i][j + 0] + bv.x;
            v.y = acc[i][j + 1] + bv.y;
            v.z = acc[i][j + 2] + bv.z;
            v.w = acc[i][j + 3] + bv.w;
            *(float4*)&C[row * (size_t)ldc + col] = v;
        }
    }
}

// ---------------------------------------------------------------------------
// RoPE in-place on q and k sections of qkv (S x 3840).
// Pair rotation: (x_d, x_{d+40}) with c = cos[s][d] (cos[d]==cos[d+40]).
// ---------------------------------------------------------------------------
__global__ __launch_bounds__(256) void rope_kernel(
    float* __restrict__ qkv,
    const float* __restrict__ cos_t,
    const float* __restrict__ sin_t)
{
    int u = blockIdx.x * 256 + threadIdx.x;
    if (u >= SEQ * NH * 40) return;
    int s   = u / (NH * 40);
    int rem = u % (NH * 40);
    int h   = rem / 40;
    int d   = rem % 40;

    float c  = cos_t[s * HD + d];
    float sn = sin_t[s * HD + d];
    size_t base = (size_t)s * LDQKV + h * HD + d;

    float q0 = qkv[base],        q1 = qkv[base + 40];
    qkv[base]        = q0 * c - q1 * sn;
    qkv[base + 40]   = q1 * c + q0 * sn;

    float k0 = qkv[base + DIMV], k1 = qkv[base + DIMV + 40];
    qkv[base + DIMV]      = k0 * c - k1 * sn;
    qkv[base + DIMV + 40] = k1 * c + k0 * sn;
}

// ---------------------------------------------------------------------------
// MFMA flash attention (bf16 inputs, fp32 accumulate).
// Block = (g, h, 128-query tile): 512 threads = 8 waves, wave w owns q rows
// [w*16, w*16+16). K/V chunks of 64 staged in LDS as bf16; V transposed so
// PV B-frags are contiguous ds_read_b128. P round-trips through per-wave
// private LDS (D-layout -> A-layout). scale = 1/80 (per reference).
// Output written into the q slot of qkv (block-private region).
// ---------------------------------------------------------------------------
__global__ __launch_bounds__(512) void attn_mfma_kernel(float* __restrict__ qkv)
{
    const int bx = blockIdx.x;
    const int qt = bx & 7;
    const int h  = (bx >> 3) & 15;
    const int g  = bx >> 7;

    __shared__ unsigned short Ks[64][104];   // K chunk, cols 80..95 zero pad
    __shared__ unsigned short Vt[80][72];    // V chunk transposed: Vt[d][k]
    __shared__ unsigned short Pl[8][16][72]; // per-wave P tile: Pl[w][q][kidx]

    const int t    = threadIdx.x;
    const int w    = t >> 6;
    const int lane = t & 63;
    const int gr   = lane >> 4;   // 0..3
    const int c15  = lane & 15;

    const size_t qrow0 = (size_t)g * GL + (size_t)qt * 128;

    // Zero-pad Ks cols 80..95 (never overwritten by staging).
    {
        int r = t >> 3, cp = t & 7;
        *(unsigned int*)&Ks[r][80 + cp * 2] = 0u;
    }

    // Q fragments: A[m][k], m = c15 (q row in wave tile), k = kk*32 + gr*8 + i.
    s16x8 qf[3];
    {
        const float* qp = qkv + (qrow0 + w * 16 + c15) * LDQKV + h * HD;
#pragma unroll
        for (int kk = 0; kk < 3; ++kk) {
            int d0 = kk * 32 + gr * 8;
            union { s16x8 v; unsigned int u[4]; } cv;
            if (d0 < 80) {
                float4 x = *(const float4*)&qp[d0];
                float4 y = *(const float4*)&qp[d0 + 4];
                cv.u[0] = pack2(x.x, x.y); cv.u[1] = pack2(x.z, x.w);
                cv.u[2] = pack2(y.x, y.y); cv.u[3] = pack2(y.z, y.w);
            } else {
                cv.u[0] = cv.u[1] = cv.u[2] = cv.u[3] = 0u;
            }
            qf[kk] = cv.v;
        }
    }

    f32x4 oacc[5];
#pragma unroll
    for (int nt = 0; nt < 5; ++nt) oacc[nt] = (f32x4){0.f, 0.f, 0.f, 0.f};
    float mrow[4], lrow[4];
#pragma unroll
    for (int r = 0; r < 4; ++r) { mrow[r] = -1e30f; lrow[r] = 0.f; }

    const float scale = 1.0f / 80.0f;

    for (int kc = 0; kc < GL / 64; ++kc) {
        __syncthreads();   // previous chunk's reads complete

        // Stage K chunk: rows coalesced (r = i/20), bf16, 8B LDS writes.
#pragma unroll
        for (int s = 0; s < 3; ++s) {
            int i = t + 512 * s;
            if (i < 1280) {
                int r = i / 20, c = i % 20;
                const float* src = qkv + ((size_t)g * GL + kc * 64 + r) * LDQKV
                                   + DIMV + h * HD + c * 4;
                float4 x = *(const float4*)src;
                unsigned int* dst = (unsigned int*)&Ks[r][c * 4];
                dst[0] = pack2(x.x, x.y);
                dst[1] = pack2(x.z, x.w);
            }
        }
        // Stage V transposed: r = lane so the b16 writes spread banks.
#pragma unroll
        for (int s = 0; s < 3; ++s) {
            int i = t + 512 * s;
            if (i < 1280) {
                int r = i & 63, c4 = i >> 6;
                const float* src = qkv + ((size_t)g * GL + kc * 64 + r) * LDQKV
                                   + 2 * DIMV + h * HD + c4 * 4;
                float4 x = *(const float4*)src;
                Vt[c4 * 4 + 0][r] = f2bf(x.x);
                Vt[c4 * 4 + 1][r] = f2bf(x.y);
                Vt[c4 * 4 + 2][r] = f2bf(x.z);
                Vt[c4 * 4 + 3][r] = f2bf(x.w);
            }
        }
        __syncthreads();

        // QK^T: S[q 16][kidx 64] per wave; 4 n-tiles x 3 k-steps.
        f32x4 sacc[4];
#pragma unroll
        for (int nt = 0; nt < 4; ++nt) {
            f32x4 a = (f32x4){0.f, 0.f, 0.f, 0.f};
#pragma unroll
            for (int kk = 0; kk < 3; ++kk) {
                s16x8 kfrag = *(const s16x8*)&Ks[nt * 16 + c15][kk * 32 + gr * 8];
                a = __builtin_amdgcn_mfma_f32_16x16x32_bf16(qf[kk], kfrag, a, 0, 0, 0);
            }
            sacc[nt] = a * scale;
        }

        // Online softmax. Row q = gr*4 + r lives on the 16 lanes sharing gr.
        float rmax[4];
#pragma unroll
        for (int r = 0; r < 4; ++r)
            rmax[r] = fmaxf(fmaxf(sacc[0][r], sacc[1][r]),
                            fmaxf(sacc[2][r], sacc[3][r]));
#pragma unroll
        for (int m = 1; m < 16; m <<= 1) {
#pragma unroll
            for (int r = 0; r < 4; ++r)
                rmax[r] = fmaxf(rmax[r], __shfl_xor(rmax[r], m, 64));
        }
        float alpha[4];
#pragma unroll
        for (int r = 0; r < 4; ++r) {
            float mnew = fmaxf(mrow[r], rmax[r]);
            alpha[r] = __expf(mrow[r] - mnew);
            mrow[r] = mnew;
        }
        float rsum[4] = {0.f, 0.f, 0.f, 0.f};
#pragma unroll
        for (int nt = 0; nt < 4; ++nt)
#pragma unroll
            for (int r = 0; r < 4; ++r) {
                float p = __expf(sacc[nt][r] - mrow[r]);
                sacc[nt][r] = p;
                rsum[r] += p;
            }
#pragma unroll
        for (int m = 1; m < 16; m <<= 1) {
#pragma unroll
            for (int r = 0; r < 4; ++r)
                rsum[r] += __shfl_xor(rsum[r], m, 64);
        }
#pragma unroll
        for (int r = 0; r < 4; ++r)
            lrow[r] = lrow[r] * alpha[r] + rsum[r];
#pragma unroll
        for (int nt = 0; nt < 5; ++nt)
#pragma unroll
            for (int r = 0; r < 4; ++r)
                oacc[nt][r] *= alpha[r];

        // P (D-layout) -> per-wave LDS -> A-layout frags. Wave-private slab.
#pragma unroll
        for (int nt = 0; nt < 4; ++nt)
#pragma unroll
            for (int r = 0; r < 4; ++r)
                Pl[w][gr * 4 + r][nt * 16 + c15] = f2bf(sacc[nt][r]);
        asm volatile("s_waitcnt lgkmcnt(0)" ::: "memory");
        __builtin_amdgcn_sched_barrier(0);
        s16x8 pa[2];
        pa[0] = *(const s16x8*)&Pl[w][c15][gr * 8];
        pa[1] = *(const s16x8*)&Pl[w][c15][32 + gr * 8];

        // PV: O[q 16][d 80] += P[16x64] * V[64x80]; 5 n-tiles x 2 k-steps.
#pragma unroll
        for (int nt = 0; nt < 5; ++nt) {
            f32x4 o = oacc[nt];
#pragma unroll
            for (int kk2 = 0; kk2 < 2; ++kk2) {
                s16x8 vfrag = *(const s16x8*)&Vt[nt * 16 + c15][kk2 * 32 + gr * 8];
                o = __builtin_amdgcn_mfma_f32_16x16x32_bf16(pa[kk2], vfrag, o, 0, 0, 0);
            }
            oacc[nt] = o;
        }
    }

    // Epilogue: normalize, write into q slot (block-private region).
    float inv[4];
#pragma unroll
    for (int r = 0; r < 4; ++r) inv[r] = 1.0f / lrow[r];
    const size_t orow0 = qrow0 + w * 16;
#pragma unroll
    for (int nt = 0; nt < 5; ++nt)
#pragma unroll
        for (int r = 0; r < 4; ++r) {
            size_t row = orow0 + gr * 4 + r;
            qkv[row * LDQKV + h * HD + nt * 16 + c15] = oacc[nt][r] * inv[r];
        }
}

// ---------------------------------------------------------------------------
// Launch
// ---------------------------------------------------------------------------
extern "C" void kernel_launch(void* const* d_in, const int* in_sizes, int n_in,
                              void* d_out, int out_size, void* d_ws, size_t ws_size,
                              hipStream_t stream)
{
    const float* hidden = (const float*)d_in[0];
    const float* cos_t  = (const float*)d_in[1];
    const float* sin_t  = (const float*)d_in[2];
    const float* w_qkv  = (const float*)d_in[3];
    const float* b_qkv  = (const float*)d_in[4];
    const float* w_proj = (const float*)d_in[5];
    const float* b_proj = (const float*)d_in[6];

    float* out = (float*)d_out;
    float* qkv = (float*)d_ws;   // (16384, 3840) fp32 scratch

    // 1) QKV projection
    {
        dim3 grid(3 * DIMV / 128, SEQ / 128);
        gemm_tile_kernel<<<grid, 256, 0, stream>>>(
            hidden, DIMV, w_qkv, 3 * DIMV, b_qkv, qkv, 3 * DIMV, DIMV);
    }
    // 2) RoPE
    {
        int n = SEQ * NH * 40;
        rope_kernel<<<(n + 255) / 256, 256, 0, stream>>>(qkv, cos_t, sin_t);
    }
    // 3) Attention (MFMA flash; writes O into q slot of qkv)
    {
        dim3 grid(NG * NH * (GL / 128));   // 2048 blocks
        attn_mfma_kernel<<<grid, 512, 0, stream>>>(qkv);
    }
    // 4) Output projection
    {
        dim3 grid(DIMV / 128, SEQ / 128);
        gemm_tile_kernel<<<grid, 256, 0, stream>>>(
            qkv, 3 * DIMV, w_proj, DIMV, b_proj, out, DIMV, DIMV);
    }
}

// Round 4
// 756.124 us; speedup vs baseline: 8.7860x; 3.9135x over previous
//
#include <hip/hip_runtime.h>
#include <cmath>

// Problem constants (S=16384, DIM=1280, H=16, D=80, G=16, L=1024)
#define SEQ   16384
#define DIMV  1280
#define NH    16
#define HD    80
#define NG    16
#define GL    1024
#define LDQKV (3*DIMV)

typedef short s16x8 __attribute__((ext_vector_type(8)));
typedef float f32x4 __attribute__((ext_vector_type(4)));

__device__ __forceinline__ unsigned short f2bf(float f) {
    union { float f; unsigned int u; } v; v.f = f;
    unsigned int u = v.u;
    return (unsigned short)((u + 0x7FFFu + ((u >> 16) & 1u)) >> 16);  // RNE
}
__device__ __forceinline__ float bf2f(unsigned short h) {
    union { unsigned int u; float f; } v; v.u = ((unsigned int)h) << 16;
    return v.f;
}
__device__ __forceinline__ unsigned int pack2(float a, float b) {
    return (unsigned int)f2bf(a) | ((unsigned int)f2bf(b) << 16);
}
__device__ __forceinline__ void gload_lds16(const void* g, void* l) {
    __builtin_amdgcn_global_load_lds(
        (const __attribute__((address_space(1))) unsigned int*)g,
        (__attribute__((address_space(3))) unsigned int*)l,
        16, 0, 0);
}

// ---------------------------------------------------------------------------
// fp32 -> bf16 convert (vectorized 8/thread)
// ---------------------------------------------------------------------------
__global__ __launch_bounds__(256) void convert_bf16_kernel(
    const float* __restrict__ src, unsigned short* __restrict__ dst, int n)
{
    int i = (blockIdx.x * 256 + threadIdx.x) * 8;
    if (i >= n) return;
    float4 a = *(const float4*)&src[i];
    float4 b = *(const float4*)&src[i + 4];
    uint4 o;
    o.x = pack2(a.x, a.y); o.y = pack2(a.z, a.w);
    o.z = pack2(b.x, b.y); o.w = pack2(b.z, b.w);
    *(uint4*)&dst[i] = o;
}

// ---------------------------------------------------------------------------
// W [K][N] fp32 -> WT [N][K] bf16 (32x32 LDS tile transpose)
// ---------------------------------------------------------------------------
__global__ __launch_bounds__(256) void transpose_bf16_kernel(
    const float* __restrict__ W, unsigned short* __restrict__ WT,
    int Kdim, int N)
{
    __shared__ float tile[32][33];
    const int bx = blockIdx.x * 32;   // N offset
    const int by = blockIdx.y * 32;   // K offset
    const int tx = threadIdx.x & 31, ty = threadIdx.x >> 5;
#pragma unroll
    for (int j = 0; j < 4; ++j)
        tile[ty + j * 8][tx] = W[(size_t)(by + ty + j * 8) * N + bx + tx];
    __syncthreads();
#pragma unroll
    for (int j = 0; j < 4; ++j)
        WT[(size_t)(bx + ty + j * 8) * Kdim + by + tx] =
            f2bf(tile[tx][ty + j * 8]);
}

// ---------------------------------------------------------------------------
// bf16 MFMA GEMM (m97 structure): C[M x N] = A[M x K] @ BT[N x K]^T + bias
// 128x128 tile, 256 thr = 4 waves (2x2), 4x4 16x16 frags/wave, BK=64.
// LDS tiles [128][64] bf16 with T2 XOR swizzle: LDS[row, Lblk] holds
// G[row, Lblk ^ (row&7)] (16B blocks) -- staged via pre-swizzled global src
// (linear global_load_lds dest), read with the same XOR. 2-way conflicts only.
// ---------------------------------------------------------------------------
template <bool BF16_OUT>
__global__ __launch_bounds__(256) void gemm_bf16_kernel(
    const unsigned short* __restrict__ A,   // [M][K] bf16
    const unsigned short* __restrict__ BT,  // [N][K] bf16
    const float* __restrict__ bias,         // [N]
    void* __restrict__ C, int ldc, int K)
{
    __shared__ unsigned short As[128 * 64];
    __shared__ unsigned short Bs[128 * 64];
    const int t    = threadIdx.x;
    const int w    = t >> 6, lane = t & 63;
    const int wr   = w >> 1, wc = w & 1;
    const int gr   = lane >> 4, c15 = lane & 15;
    const int bm   = blockIdx.y * 128, bn = blockIdx.x * 128;

    f32x4 acc[4][4];
#pragma unroll
    for (int m = 0; m < 4; ++m)
#pragma unroll
        for (int n = 0; n < 4; ++n) acc[m][n] = (f32x4){0.f, 0.f, 0.f, 0.f};

    for (int kt = 0; kt < K; kt += 64) {
        // Stage 16KB A + 16KB B; per thread 4+4 x 16B direct-to-LDS.
#pragma unroll
        for (int i = 0; i < 4; ++i) {
            int idx = t + i * 256;              // 16B-block index in tile
            int row = idx >> 3;                 // 0..127
            int cb  = ((idx & 7) ^ (row & 7)) << 4;   // pre-swizzled src col byte
            gload_lds16((const char*)A + ((size_t)(bm + row) * K + kt) * 2 + cb,
                        (char*)As + idx * 16);
            gload_lds16((const char*)BT + ((size_t)(bn + row) * K + kt) * 2 + cb,
                        (char*)Bs + idx * 16);
        }
        __syncthreads();

#pragma unroll
        for (int ks = 0; ks < 2; ++ks) {
            s16x8 af[4], bf_[4];
#pragma unroll
            for (int m = 0; m < 4; ++m) {
                int row = wr * 64 + m * 16 + c15;
                int col = (ks * 64 + gr * 16) ^ ((row & 7) << 4);
                af[m] = *(const s16x8*)((const char*)As + row * 128 + col);
            }
#pragma unroll
            for (int n = 0; n < 4; ++n) {
                int row = wc * 64 + n * 16 + c15;
                int col = (ks * 64 + gr * 16) ^ ((row & 7) << 4);
                bf_[n] = *(const s16x8*)((const char*)Bs + row * 128 + col);
            }
#pragma unroll
            for (int m = 0; m < 4; ++m)
#pragma unroll
                for (int n = 0; n < 4; ++n)
                    acc[m][n] = __builtin_amdgcn_mfma_f32_16x16x32_bf16(
                        af[m], bf_[n], acc[m][n], 0, 0, 0);
        }
        __syncthreads();
    }

    // Epilogue: C[m][n], row = bm + wr*64 + m*16 + gr*4 + j, col = bn + wc*64 + n*16 + c15.
#pragma unroll
    for (int m = 0; m < 4; ++m) {
        int row0 = bm + wr * 64 + m * 16 + gr * 4;
#pragma unroll
        for (int n = 0; n < 4; ++n) {
            int col = bn + wc * 64 + n * 16 + c15;
            float bv = bias[col];
#pragma unroll
            for (int j = 0; j < 4; ++j) {
                float v = acc[m][n][j] + bv;
                if (BF16_OUT)
                    ((unsigned short*)C)[(size_t)(row0 + j) * ldc + col] = f2bf(v);
                else
                    ((float*)C)[(size_t)(row0 + j) * ldc + col] = v;
            }
        }
    }
}

// ---------------------------------------------------------------------------
// RoPE in-place on bf16 qkv: pairs (d, d+40), thread handles 2 consecutive d.
// ---------------------------------------------------------------------------
__global__ __launch_bounds__(256) void rope_bf16_kernel(
    unsigned short* __restrict__ qkv,
    const float* __restrict__ cos_t,
    const float* __restrict__ sin_t)
{
    int u = blockIdx.x * 256 + threadIdx.x;
    if (u >= SEQ * NH * 20) return;
    int s   = u / (NH * 20);
    int rem = u % (NH * 20);
    int h   = rem / 20;
    int d   = (rem % 20) * 2;

    float2 c  = *(const float2*)&cos_t[s * HD + d];
    float2 sn = *(const float2*)&sin_t[s * HD + d];
    size_t base = (size_t)s * LDQKV + h * HD + d;

#pragma unroll
    for (int part = 0; part < 2; ++part) {
        size_t b = base + part * DIMV;          // q then k
        unsigned int lo = *(unsigned int*)&qkv[b];
        unsigned int hi = *(unsigned int*)&qkv[b + 40];
        float x0 = bf2f((unsigned short)lo), x1 = bf2f((unsigned short)(lo >> 16));
        float y0 = bf2f((unsigned short)hi), y1 = bf2f((unsigned short)(hi >> 16));
        *(unsigned int*)&qkv[b]      = pack2(x0 * c.x - y0 * sn.x, x1 * c.y - y1 * sn.y);
        *(unsigned int*)&qkv[b + 40] = pack2(y0 * c.x + x0 * sn.x, y1 * c.y + x1 * sn.y);
    }
}

// ---------------------------------------------------------------------------
// MFMA flash attention (bf16 in/out, fp32 accumulate). Same structure as R3,
// now reading bf16 qkv directly (no convert VALU) and writing bf16 ao.
// ---------------------------------------------------------------------------
__global__ __launch_bounds__(512) void attn_mfma_kernel(
    const unsigned short* __restrict__ qkv,
    unsigned short* __restrict__ ao)
{
    const int bx = blockIdx.x;
    const int qt = bx & 7;
    const int h  = (bx >> 3) & 15;
    const int g  = bx >> 7;

    __shared__ unsigned short Ks[64][104];   // cols 80..95 zero pad
    __shared__ unsigned short Vt[80][72];    // V transposed: Vt[d][k]
    __shared__ unsigned short Pl[8][16][72]; // per-wave P tile

    const int t    = threadIdx.x;
    const int w    = t >> 6;
    const int lane = t & 63;
    const int gr   = lane >> 4;
    const int c15  = lane & 15;

    const size_t qrow0 = (size_t)g * GL + (size_t)qt * 128;

    {   // zero-pad Ks cols 80..95
        int r = t >> 3, cp = t & 7;
        *(unsigned int*)&Ks[r][80 + cp * 2] = 0u;
    }

    // Q fragments direct from bf16 global.
    s16x8 qf[3];
    {
        const unsigned short* qp = qkv + (qrow0 + w * 16 + c15) * LDQKV + h * HD;
#pragma unroll
        for (int kk = 0; kk < 3; ++kk) {
            int d0 = kk * 32 + gr * 8;
            if (d0 < 80) qf[kk] = *(const s16x8*)&qp[d0];
            else         qf[kk] = (s16x8){0,0,0,0,0,0,0,0};
        }
    }

    f32x4 oacc[5];
#pragma unroll
    for (int nt = 0; nt < 5; ++nt) oacc[nt] = (f32x4){0.f, 0.f, 0.f, 0.f};
    float mrow[4], lrow[4];
#pragma unroll
    for (int r = 0; r < 4; ++r) { mrow[r] = -1e30f; lrow[r] = 0.f; }

    const float scale = 1.0f / 80.0f;

    for (int kc = 0; kc < GL / 64; ++kc) {
        __syncthreads();

        // Stage K: 640 x 16B, coalesced rows.
#pragma unroll
        for (int s = 0; s < 2; ++s) {
            int i = t + 512 * s;
            if (i < 640) {
                int r = i / 10, cc = i % 10;
                const unsigned short* src =
                    qkv + ((size_t)g * GL + kc * 64 + r) * LDQKV + DIMV + h * HD + cc * 8;
                *(uint4*)&Ks[r][cc * 8] = *(const uint4*)src;
            }
        }
        // Stage V transposed: lane-major rows for spread LDS banks.
#pragma unroll
        for (int s = 0; s < 2; ++s) {
            int i = t + 512 * s;
            if (i < 640) {
                int r = i & 63, c8 = i >> 6;
                const unsigned short* src =
                    qkv + ((size_t)g * GL + kc * 64 + r) * LDQKV + 2 * DIMV + h * HD + c8 * 8;
                uint4 x = *(const uint4*)src;
                Vt[c8 * 8 + 0][r] = (unsigned short)(x.x);
                Vt[c8 * 8 + 1][r] = (unsigned short)(x.x >> 16);
                Vt[c8 * 8 + 2][r] = (unsigned short)(x.y);
                Vt[c8 * 8 + 3][r] = (unsigned short)(x.y >> 16);
                Vt[c8 * 8 + 4][r] = (unsigned short)(x.z);
                Vt[c8 * 8 + 5][r] = (unsigned short)(x.z >> 16);
                Vt[c8 * 8 + 6][r] = (unsigned short)(x.w);
                Vt[c8 * 8 + 7][r] = (unsigned short)(x.w >> 16);
            }
        }
        __syncthreads();

        // QK^T
        f32x4 sacc[4];
#pragma unroll
        for (int nt = 0; nt < 4; ++nt) {
            f32x4 a = (f32x4){0.f, 0.f, 0.f, 0.f};
#pragma unroll
            for (int kk = 0; kk < 3; ++kk) {
                s16x8 kfrag = *(const s16x8*)&Ks[nt * 16 + c15][kk * 32 + gr * 8];
                a = __builtin_amdgcn_mfma_f32_16x16x32_bf16(qf[kk], kfrag, a, 0, 0, 0);
            }
            sacc[nt] = a * scale;
        }

        // Online softmax (16-lane row groups).
        float rmax[4];
#pragma unroll
        for (int r = 0; r < 4; ++r)
            rmax[r] = fmaxf(fmaxf(sacc[0][r], sacc[1][r]),
                            fmaxf(sacc[2][r], sacc[3][r]));
#pragma unroll
        for (int m = 1; m < 16; m <<= 1)
#pragma unroll
            for (int r = 0; r < 4; ++r)
                rmax[r] = fmaxf(rmax[r], __shfl_xor(rmax[r], m, 64));
        float alpha[4];
#pragma unroll
        for (int r = 0; r < 4; ++r) {
            float mnew = fmaxf(mrow[r], rmax[r]);
            alpha[r] = __expf(mrow[r] - mnew);
            mrow[r] = mnew;
        }
        float rsum[4] = {0.f, 0.f, 0.f, 0.f};
#pragma unroll
        for (int nt = 0; nt < 4; ++nt)
#pragma unroll
            for (int r = 0; r < 4; ++r) {
                float p = __expf(sacc[nt][r] - mrow[r]);
                sacc[nt][r] = p;
                rsum[r] += p;
            }
#pragma unroll
        for (int m = 1; m < 16; m <<= 1)
#pragma unroll
            for (int r = 0; r < 4; ++r)
                rsum[r] += __shfl_xor(rsum[r], m, 64);
#pragma unroll
        for (int r = 0; r < 4; ++r)
            lrow[r] = lrow[r] * alpha[r] + rsum[r];
#pragma unroll
        for (int nt = 0; nt < 5; ++nt)
#pragma unroll
            for (int r = 0; r < 4; ++r)
                oacc[nt][r] *= alpha[r];

        // P -> wave-private LDS -> A-layout frags.
#pragma unroll
        for (int nt = 0; nt < 4; ++nt)
#pragma unroll
            for (int r = 0; r < 4; ++r)
                Pl[w][gr * 4 + r][nt * 16 + c15] = f2bf(sacc[nt][r]);
        asm volatile("s_waitcnt lgkmcnt(0)" ::: "memory");
        __builtin_amdgcn_sched_barrier(0);
        s16x8 pa[2];
        pa[0] = *(const s16x8*)&Pl[w][c15][gr * 8];
        pa[1] = *(const s16x8*)&Pl[w][c15][32 + gr * 8];

        // PV
#pragma unroll
        for (int nt = 0; nt < 5; ++nt) {
            f32x4 o = oacc[nt];
#pragma unroll
            for (int kk2 = 0; kk2 < 2; ++kk2) {
                s16x8 vfrag = *(const s16x8*)&Vt[nt * 16 + c15][kk2 * 32 + gr * 8];
                o = __builtin_amdgcn_mfma_f32_16x16x32_bf16(pa[kk2], vfrag, o, 0, 0, 0);
            }
            oacc[nt] = o;
        }
    }

    // Epilogue: normalize, write bf16 into compact ao [SEQ][1280].
    float inv[4];
#pragma unroll
    for (int r = 0; r < 4; ++r) inv[r] = 1.0f / lrow[r];
    const size_t orow0 = qrow0 + w * 16;
#pragma unroll
    for (int nt = 0; nt < 5; ++nt)
#pragma unroll
        for (int r = 0; r < 4; ++r)
            ao[(orow0 + gr * 4 + r) * DIMV + h * HD + nt * 16 + c15] =
                f2bf(oacc[nt][r] * inv[r]);
}

// ---------------------------------------------------------------------------
// Launch
// ---------------------------------------------------------------------------
extern "C" void kernel_launch(void* const* d_in, const int* in_sizes, int n_in,
                              void* d_out, int out_size, void* d_ws, size_t ws_size,
                              hipStream_t stream)
{
    const float* hidden = (const float*)d_in[0];
    const float* cos_t  = (const float*)d_in[1];
    const float* sin_t  = (const float*)d_in[2];
    const float* w_qkv  = (const float*)d_in[3];
    const float* b_qkv  = (const float*)d_in[4];
    const float* w_proj = (const float*)d_in[5];
    const float* b_proj = (const float*)d_in[6];

    float* out = (float*)d_out;

    // ws layout (bytes): qkv_bf 125829120 | hbf 41943040 | ao_bf 41943040
    //                    | wqkvT 9830400 | wprojT 3276800  (total ~213 MB)
    char* ws = (char*)d_ws;
    unsigned short* qkv_bf = (unsigned short*)(ws);
    unsigned short* hbf    = (unsigned short*)(ws + 125829120);
    unsigned short* ao_bf  = (unsigned short*)(ws + 167772160);
    unsigned short* wqkvT  = (unsigned short*)(ws + 209715200);
    unsigned short* wprojT = (unsigned short*)(ws + 219545600);

    // 0) Converts / transposes.
    {
        int n = SEQ * DIMV;                       // 20.97M
        convert_bf16_kernel<<<n / 8 / 256, 256, 0, stream>>>(hidden, hbf, n);
        transpose_bf16_kernel<<<dim3(3 * DIMV / 32, DIMV / 32), 256, 0, stream>>>(
            w_qkv, wqkvT, DIMV, 3 * DIMV);
        transpose_bf16_kernel<<<dim3(DIMV / 32, DIMV / 32), 256, 0, stream>>>(
            w_proj, wprojT, DIMV, DIMV);
    }
    // 1) QKV projection (bf16 MFMA), bf16 out.
    gemm_bf16_kernel<true><<<dim3(3 * DIMV / 128, SEQ / 128), 256, 0, stream>>>(
        hbf, wqkvT, b_qkv, qkv_bf, 3 * DIMV, DIMV);
    // 2) RoPE in-place on bf16 qkv.
    {
        int n = SEQ * NH * 20;
        rope_bf16_kernel<<<n / 256, 256, 0, stream>>>(qkv_bf, cos_t, sin_t);
    }
    // 3) Attention -> ao_bf.
    attn_mfma_kernel<<<dim3(NG * NH * (GL / 128)), 512, 0, stream>>>(qkv_bf, ao_bf);
    // 4) Output projection (bf16 MFMA), fp32 out.
    gemm_bf16_kernel<false><<<dim3(DIMV / 128, SEQ / 128), 256, 0, stream>>>(
        ao_bf, wprojT, b_proj, out, DIMV, DIMV);
}

// Round 6
// 740.894 us; speedup vs baseline: 8.9666x; 1.0206x over previous
//
#include <hip/hip_runtime.h>
#include <cmath>

// Problem constants (S=16384, DIM=1280, H=16, D=80, G=16, L=1024)
#define SEQ   16384
#define DIMV  1280
#define NH    16
#define HD    80
#define NG    16
#define GL    1024
#define LDQKV (3*DIMV)

typedef short s16x8 __attribute__((ext_vector_type(8)));
typedef float f32x4 __attribute__((ext_vector_type(4)));

__device__ __forceinline__ unsigned short f2bf(float f) {
    union { float f; unsigned int u; } v; v.f = f;
    unsigned int u = v.u;
    return (unsigned short)((u + 0x7FFFu + ((u >> 16) & 1u)) >> 16);  // RNE
}
__device__ __forceinline__ float bf2f(unsigned short h) {
    union { unsigned int u; float f; } v; v.u = ((unsigned int)h) << 16;
    return v.f;
}
__device__ __forceinline__ unsigned int pack2(float a, float b) {
    return (unsigned int)f2bf(a) | ((unsigned int)f2bf(b) << 16);
}
__device__ __forceinline__ void gload_lds16(const void* g, void* l) {
    __builtin_amdgcn_global_load_lds(
        (const __attribute__((address_space(1))) unsigned int*)g,
        (__attribute__((address_space(3))) unsigned int*)l,
        16, 0, 0);
}

// ---------------------------------------------------------------------------
// fp32 -> bf16 convert (vectorized 8/thread)
// ---------------------------------------------------------------------------
__global__ __launch_bounds__(256) void convert_bf16_kernel(
    const float* __restrict__ src, unsigned short* __restrict__ dst, int n)
{
    int i = (blockIdx.x * 256 + threadIdx.x) * 8;
    if (i >= n) return;
    float4 a = *(const float4*)&src[i];
    float4 b = *(const float4*)&src[i + 4];
    uint4 o;
    o.x = pack2(a.x, a.y); o.y = pack2(a.z, a.w);
    o.z = pack2(b.x, b.y); o.w = pack2(b.z, b.w);
    *(uint4*)&dst[i] = o;
}

// ---------------------------------------------------------------------------
// W [K][N] fp32 -> WT [N][K] bf16 (32x32 LDS tile transpose)
// ---------------------------------------------------------------------------
__global__ __launch_bounds__(256) void transpose_bf16_kernel(
    const float* __restrict__ W, unsigned short* __restrict__ WT,
    int Kdim, int N)
{
    __shared__ float tile[32][33];
    const int bx = blockIdx.x * 32;   // N offset
    const int by = blockIdx.y * 32;   // K offset
    const int tx = threadIdx.x & 31, ty = threadIdx.x >> 5;
#pragma unroll
    for (int j = 0; j < 4; ++j)
        tile[ty + j * 8][tx] = W[(size_t)(by + ty + j * 8) * N + bx + tx];
    __syncthreads();
#pragma unroll
    for (int j = 0; j < 4; ++j)
        WT[(size_t)(bx + ty + j * 8) * Kdim + by + tx] =
            f2bf(tile[tx][ty + j * 8]);
}

// ---------------------------------------------------------------------------
// bf16 MFMA GEMM (m97 structure): C[M x N] = A[M x K] @ BT[N x K]^T + bias
// ---------------------------------------------------------------------------
template <bool BF16_OUT>
__global__ __launch_bounds__(256) void gemm_bf16_kernel(
    const unsigned short* __restrict__ A,   // [M][K] bf16
    const unsigned short* __restrict__ BT,  // [N][K] bf16
    const float* __restrict__ bias,         // [N]
    void* __restrict__ C, int ldc, int K)
{
    __shared__ unsigned short As[128 * 64];
    __shared__ unsigned short Bs[128 * 64];
    const int t    = threadIdx.x;
    const int w    = t >> 6, lane = t & 63;
    const int wr   = w >> 1, wc = w & 1;
    const int gr   = lane >> 4, c15 = lane & 15;
    const int bm   = blockIdx.y * 128, bn = blockIdx.x * 128;

    f32x4 acc[4][4];
#pragma unroll
    for (int m = 0; m < 4; ++m)
#pragma unroll
        for (int n = 0; n < 4; ++n) acc[m][n] = (f32x4){0.f, 0.f, 0.f, 0.f};

    for (int kt = 0; kt < K; kt += 64) {
#pragma unroll
        for (int i = 0; i < 4; ++i) {
            int idx = t + i * 256;
            int row = idx >> 3;
            int cb  = ((idx & 7) ^ (row & 7)) << 4;
            gload_lds16((const char*)A + ((size_t)(bm + row) * K + kt) * 2 + cb,
                        (char*)As + idx * 16);
            gload_lds16((const char*)BT + ((size_t)(bn + row) * K + kt) * 2 + cb,
                        (char*)Bs + idx * 16);
        }
        __syncthreads();

#pragma unroll
        for (int ks = 0; ks < 2; ++ks) {
            s16x8 af[4], bf_[4];
#pragma unroll
            for (int m = 0; m < 4; ++m) {
                int row = wr * 64 + m * 16 + c15;
                int col = (ks * 64 + gr * 16) ^ ((row & 7) << 4);
                af[m] = *(const s16x8*)((const char*)As + row * 128 + col);
            }
#pragma unroll
            for (int n = 0; n < 4; ++n) {
                int row = wc * 64 + n * 16 + c15;
                int col = (ks * 64 + gr * 16) ^ ((row & 7) << 4);
                bf_[n] = *(const s16x8*)((const char*)Bs + row * 128 + col);
            }
#pragma unroll
            for (int m = 0; m < 4; ++m)
#pragma unroll
                for (int n = 0; n < 4; ++n)
                    acc[m][n] = __builtin_amdgcn_mfma_f32_16x16x32_bf16(
                        af[m], bf_[n], acc[m][n], 0, 0, 0);
        }
        __syncthreads();
    }

#pragma unroll
    for (int m = 0; m < 4; ++m) {
        int row0 = bm + wr * 64 + m * 16 + gr * 4;
#pragma unroll
        for (int n = 0; n < 4; ++n) {
            int col = bn + wc * 64 + n * 16 + c15;
            float bv = bias[col];
#pragma unroll
            for (int j = 0; j < 4; ++j) {
                float v = acc[m][n][j] + bv;
                if (BF16_OUT)
                    ((unsigned short*)C)[(size_t)(row0 + j) * ldc + col] = f2bf(v);
                else
                    ((float*)C)[(size_t)(row0 + j) * ldc + col] = v;
            }
        }
    }
}

// ---------------------------------------------------------------------------
// RoPE in-place on bf16 qkv
// ---------------------------------------------------------------------------
__global__ __launch_bounds__(256) void rope_bf16_kernel(
    unsigned short* __restrict__ qkv,
    const float* __restrict__ cos_t,
    const float* __restrict__ sin_t)
{
    int u = blockIdx.x * 256 + threadIdx.x;
    if (u >= SEQ * NH * 20) return;
    int s   = u / (NH * 20);
    int rem = u % (NH * 20);
    int h   = rem / 20;
    int d   = (rem % 20) * 2;

    float2 c  = *(const float2*)&cos_t[s * HD + d];
    float2 sn = *(const float2*)&sin_t[s * HD + d];
    size_t base = (size_t)s * LDQKV + h * HD + d;

#pragma unroll
    for (int part = 0; part < 2; ++part) {
        size_t b = base + part * DIMV;
        unsigned int lo = *(unsigned int*)&qkv[b];
        unsigned int hi = *(unsigned int*)&qkv[b + 40];
        float x0 = bf2f((unsigned short)lo), x1 = bf2f((unsigned short)(lo >> 16));
        float y0 = bf2f((unsigned short)hi), y1 = bf2f((unsigned short)(hi >> 16));
        *(unsigned int*)&qkv[b]      = pack2(x0 * c.x - y0 * sn.x, x1 * c.y - y1 * sn.y);
        *(unsigned int*)&qkv[b + 40] = pack2(y0 * c.x + x0 * sn.x, y1 * c.y + x1 * sn.y);
    }
}

// ---------------------------------------------------------------------------
// MFMA flash attention (bf16 in/out, fp32 accumulate).
//  - Async stage-split (T14): chunk kc+1's K/V global loads issued during
//    chunk kc's compute (into regs); regs->LDS write after next top barrier.
//  - Defer-max (T13): skip mrow update / alpha / O,l rescale when no row's
//    max grew by > 8 (wave-uniform __any branch).
// ---------------------------------------------------------------------------
__global__ __launch_bounds__(512) void attn_mfma_kernel(
    const unsigned short* __restrict__ qkv,
    unsigned short* __restrict__ ao)
{
    const int bx = blockIdx.x;
    const int qt = bx & 7;
    const int h  = (bx >> 3) & 15;
    const int g  = bx >> 7;

    __shared__ unsigned short Ks[64][104];   // cols 80..95 zero pad
    __shared__ unsigned short Vt[80][72];    // V transposed: Vt[d][k]
    __shared__ unsigned short Pl[8][16][72]; // per-wave P tile

    const int t    = threadIdx.x;
    const int w    = t >> 6;
    const int lane = t & 63;
    const int gr   = lane >> 4;
    const int c15  = lane & 15;

    const size_t qrow0 = (size_t)g * GL + (size_t)qt * 128;
    const unsigned short* kvbase = qkv + (size_t)g * GL * LDQKV;

    {   // zero-pad Ks cols 80..95
        int r = t >> 3, cp = t & 7;
        *(unsigned int*)&Ks[r][80 + cp * 2] = 0u;
    }

    // Per-thread staging geometry (constant across chunks).
    const int kr0_r = t / 10,         kr0_c = t % 10;
    const int kr1_r = (t + 512) / 10, kr1_c = (t + 512) % 10;
    const int vr_r  = t & 63;
    const int vc0   = t >> 6;
    const int vc1   = 8 + (t >> 6);
    const bool two  = (t < 128);

    const size_t offK0 = (size_t)kr0_r * LDQKV + DIMV + h * HD + kr0_c * 8;
    const size_t offK1 = (size_t)kr1_r * LDQKV + DIMV + h * HD + kr1_c * 8;
    const size_t offV0 = (size_t)vr_r  * LDQKV + 2 * DIMV + h * HD + vc0 * 8;
    const size_t offV1 = (size_t)vr_r  * LDQKV + 2 * DIMV + h * HD + vc1 * 8;

    uint4 kr0, kr1, vr0, vr1;

    // Prologue: issue chunk 0 loads.
    {
        const unsigned short* base = kvbase;
        kr0 = *(const uint4*)&base[offK0];
        vr0 = *(const uint4*)&base[offV0];
        if (two) {
            kr1 = *(const uint4*)&base[offK1];
            vr1 = *(const uint4*)&base[offV1];
        }
    }

    // Q fragments direct from bf16 global.
    s16x8 qf[3];
    {
        const unsigned short* qp = qkv + (qrow0 + w * 16 + c15) * LDQKV + h * HD;
#pragma unroll
        for (int kk = 0; kk < 3; ++kk) {
            int d0 = kk * 32 + gr * 8;
            if (d0 < 80) qf[kk] = *(const s16x8*)&qp[d0];
            else         qf[kk] = (s16x8){0,0,0,0,0,0,0,0};
        }
    }

    f32x4 oacc[5];
#pragma unroll
    for (int nt = 0; nt < 5; ++nt) oacc[nt] = (f32x4){0.f, 0.f, 0.f, 0.f};
    float mrow[4], lrow[4];
#pragma unroll
    for (int r = 0; r < 4; ++r) { mrow[r] = -1e30f; lrow[r] = 0.f; }

    const float scale = 1.0f / 80.0f;

    for (int kc = 0; kc < GL / 64; ++kc) {
        __syncthreads();   // previous chunk's LDS reads complete

        // Write prefetched regs -> LDS.
        *(uint4*)&Ks[kr0_r][kr0_c * 8] = kr0;
        if (two) *(uint4*)&Ks[kr1_r][kr1_c * 8] = kr1;
        {
            uint4 x = vr0;
            Vt[vc0 * 8 + 0][vr_r] = (unsigned short)(x.x);
            Vt[vc0 * 8 + 1][vr_r] = (unsigned short)(x.x >> 16);
            Vt[vc0 * 8 + 2][vr_r] = (unsigned short)(x.y);
            Vt[vc0 * 8 + 3][vr_r] = (unsigned short)(x.y >> 16);
            Vt[vc0 * 8 + 4][vr_r] = (unsigned short)(x.z);
            Vt[vc0 * 8 + 5][vr_r] = (unsigned short)(x.z >> 16);
            Vt[vc0 * 8 + 6][vr_r] = (unsigned short)(x.w);
            Vt[vc0 * 8 + 7][vr_r] = (unsigned short)(x.w >> 16);
        }
        if (two) {
            uint4 x = vr1;
            Vt[vc1 * 8 + 0][vr_r] = (unsigned short)(x.x);
            Vt[vc1 * 8 + 1][vr_r] = (unsigned short)(x.x >> 16);
            Vt[vc1 * 8 + 2][vr_r] = (unsigned short)(x.y);
            Vt[vc1 * 8 + 3][vr_r] = (unsigned short)(x.y >> 16);
            Vt[vc1 * 8 + 4][vr_r] = (unsigned short)(x.z);
            Vt[vc1 * 8 + 5][vr_r] = (unsigned short)(x.z >> 16);
            Vt[vc1 * 8 + 6][vr_r] = (unsigned short)(x.w);
            Vt[vc1 * 8 + 7][vr_r] = (unsigned short)(x.w >> 16);
        }
        __syncthreads();   // LDS ready

        // Issue next chunk's loads (latency hides under compute below).
        if (kc + 1 < GL / 64) {
            const unsigned short* base = kvbase + (size_t)(kc + 1) * 64 * LDQKV;
            kr0 = *(const uint4*)&base[offK0];
            vr0 = *(const uint4*)&base[offV0];
            if (two) {
                kr1 = *(const uint4*)&base[offK1];
                vr1 = *(const uint4*)&base[offV1];
            }
        }

        // QK^T
        f32x4 sacc[4];
#pragma unroll
        for (int nt = 0; nt < 4; ++nt) {
            f32x4 a = (f32x4){0.f, 0.f, 0.f, 0.f};
#pragma unroll
            for (int kk = 0; kk < 3; ++kk) {
                s16x8 kfrag = *(const s16x8*)&Ks[nt * 16 + c15][kk * 32 + gr * 8];
                a = __builtin_amdgcn_mfma_f32_16x16x32_bf16(qf[kk], kfrag, a, 0, 0, 0);
            }
            sacc[nt] = a * scale;
        }

        // Row max (16-lane groups; row q = gr*4 + r).
        float rmax[4];
#pragma unroll
        for (int r = 0; r < 4; ++r)
            rmax[r] = fmaxf(fmaxf(sacc[0][r], sacc[1][r]),
                            fmaxf(sacc[2][r], sacc[3][r]));
#pragma unroll
        for (int m = 1; m < 16; m <<= 1)
#pragma unroll
            for (int r = 0; r < 4; ++r)
                rmax[r] = fmaxf(rmax[r], __shfl_xor(rmax[r], m, 64));

        // Defer-max: only rescale when some row's max grew past threshold.
        bool need = false;
#pragma unroll
        for (int r = 0; r < 4; ++r)
            need = need || (rmax[r] > mrow[r] + 8.0f);
        if (__any(need)) {
            float alpha[4];
#pragma unroll
            for (int r = 0; r < 4; ++r) {
                float mnew = fmaxf(mrow[r], rmax[r]);
                alpha[r] = __expf(mrow[r] - mnew);
                mrow[r] = mnew;
                lrow[r] *= alpha[r];
            }
#pragma unroll
            for (int nt = 0; nt < 5; ++nt)
#pragma unroll
                for (int r = 0; r < 4; ++r)
                    oacc[nt][r] *= alpha[r];
        }

        // P = exp(S - mrow), row sums.
        float rsum[4] = {0.f, 0.f, 0.f, 0.f};
#pragma unroll
        for (int nt = 0; nt < 4; ++nt)
#pragma unroll
            for (int r = 0; r < 4; ++r) {
                float p = __expf(sacc[nt][r] - mrow[r]);
                sacc[nt][r] = p;
                rsum[r] += p;
            }
#pragma unroll
        for (int m = 1; m < 16; m <<= 1)
#pragma unroll
            for (int r = 0; r < 4; ++r)
                rsum[r] += __shfl_xor(rsum[r], m, 64);
#pragma unroll
        for (int r = 0; r < 4; ++r)
            lrow[r] += rsum[r];

        // P -> wave-private LDS -> A-layout frags.
#pragma unroll
        for (int nt = 0; nt < 4; ++nt)
#pragma unroll
            for (int r = 0; r < 4; ++r)
                Pl[w][gr * 4 + r][nt * 16 + c15] = f2bf(sacc[nt][r]);
        asm volatile("s_waitcnt lgkmcnt(0)" ::: "memory");
        __builtin_amdgcn_sched_barrier(0);
        s16x8 pa[2];
        pa[0] = *(const s16x8*)&Pl[w][c15][gr * 8];
        pa[1] = *(const s16x8*)&Pl[w][c15][32 + gr * 8];

        // PV
#pragma unroll
        for (int nt = 0; nt < 5; ++nt) {
            f32x4 o = oacc[nt];
#pragma unroll
            for (int kk2 = 0; kk2 < 2; ++kk2) {
                s16x8 vfrag = *(const s16x8*)&Vt[nt * 16 + c15][kk2 * 32 + gr * 8];
                o = __builtin_amdgcn_mfma_f32_16x16x32_bf16(pa[kk2], vfrag, o, 0, 0, 0);
            }
            oacc[nt] = o;
        }
    }

    // Epilogue: normalize, write bf16 into compact ao [SEQ][1280].
    float inv[4];
#pragma unroll
    for (int r = 0; r < 4; ++r) inv[r] = 1.0f / lrow[r];
    const size_t orow0 = qrow0 + w * 16;
#pragma unroll
    for (int nt = 0; nt < 5; ++nt)
#pragma unroll
        for (int r = 0; r < 4; ++r)
            ao[(orow0 + gr * 4 + r) * DIMV + h * HD + nt * 16 + c15] =
                f2bf(oacc[nt][r] * inv[r]);
}

// ---------------------------------------------------------------------------
// Launch
// ---------------------------------------------------------------------------
extern "C" void kernel_launch(void* const* d_in, const int* in_sizes, int n_in,
                              void* d_out, int out_size, void* d_ws, size_t ws_size,
                              hipStream_t stream)
{
    const float* hidden = (const float*)d_in[0];
    const float* cos_t  = (const float*)d_in[1];
    const float* sin_t  = (const float*)d_in[2];
    const float* w_qkv  = (const float*)d_in[3];
    const float* b_qkv  = (const float*)d_in[4];
    const float* w_proj = (const float*)d_in[5];
    const float* b_proj = (const float*)d_in[6];

    float* out = (float*)d_out;

    // ws layout (bytes): qkv_bf 125829120 | hbf 41943040 | ao_bf 41943040
    //                    | wqkvT 9830400 | wprojT 3276800  (total ~213 MB)
    char* ws = (char*)d_ws;
    unsigned short* qkv_bf = (unsigned short*)(ws);
    unsigned short* hbf    = (unsigned short*)(ws + 125829120);
    unsigned short* ao_bf  = (unsigned short*)(ws + 167772160);
    unsigned short* wqkvT  = (unsigned short*)(ws + 209715200);
    unsigned short* wprojT = (unsigned short*)(ws + 219545600);

    // 0) Converts / transposes.
    {
        int n = SEQ * DIMV;
        convert_bf16_kernel<<<n / 8 / 256, 256, 0, stream>>>(hidden, hbf, n);
        transpose_bf16_kernel<<<dim3(3 * DIMV / 32, DIMV / 32), 256, 0, stream>>>(
            w_qkv, wqkvT, DIMV, 3 * DIMV);
        transpose_bf16_kernel<<<dim3(DIMV / 32, DIMV / 32), 256, 0, stream>>>(
            w_proj, wprojT, DIMV, DIMV);
    }
    // 1) QKV projection (bf16 MFMA), bf16 out.
    gemm_bf16_kernel<true><<<dim3(3 * DIMV / 128, SEQ / 128), 256, 0, stream>>>(
        hbf, wqkvT, b_qkv, qkv_bf, 3 * DIMV, DIMV);
    // 2) RoPE in-place on bf16 qkv.
    {
        int n = SEQ * NH * 20;
        rope_bf16_kernel<<<n / 256, 256, 0, stream>>>(qkv_bf, cos_t, sin_t);
    }
    // 3) Attention -> ao_bf.
    attn_mfma_kernel<<<dim3(NG * NH * (GL / 128)), 512, 0, stream>>>(qkv_bf, ao_bf);
    // 4) Output projection (bf16 MFMA), fp32 out.
    gemm_bf16_kernel<false><<<dim3(DIMV / 128, SEQ / 128), 256, 0, stream>>>(
        ao_bf, wprojT, b_proj, out, DIMV, DIMV);
}